// Round 18
// baseline (3436.580 us; speedup 1.0000x reference)
//
#include <hip/hip_runtime.h>
#include <hip/hip_bf16.h>
#include <math.h>

#define B_  256
#define T_  256
#define IN_ 4
#define HP_ 64
#define E_  512
#define H_  1024
#define D_  4

typedef __hip_bfloat16 bf16;
typedef _Float16 f16;
typedef _Float16 f16x8 __attribute__((ext_vector_type(8)));
typedef float f32x4 __attribute__((ext_vector_type(4)));

// ---------------------------------------------------------------------------
// Dual-dtype load helpers: flag!=0 -> input arrays are bf16, else fp32.
// ---------------------------------------------------------------------------
__device__ __forceinline__ float load1(const void* p, size_t idx, bool isb) {
    if (isb) {
        unsigned int u = ((const unsigned short*)p)[idx];
        return __uint_as_float(u << 16);
    }
    return ((const float*)p)[idx];
}

__device__ __forceinline__ float4 load4(const void* p, size_t idx, bool isb) {
    if (isb) {
        ushort4 u = *(const ushort4*)((const unsigned short*)p + idx);
        float4 r;
        r.x = __uint_as_float(((unsigned int)u.x) << 16);
        r.y = __uint_as_float(((unsigned int)u.y) << 16);
        r.z = __uint_as_float(((unsigned int)u.z) << 16);
        r.w = __uint_as_float(((unsigned int)u.w) << 16);
        return r;
    }
    return *((const float4*)p + (idx >> 2));
}

// ---------------------------------------------------------------------------
// Exact 3-plane f16 split:  x ~= h + lb*2^-11  (lb pre-scaled by 2^11).
// x*w = h*wh + (h*2^-11)*(wl*2^11) + (l*2^11)*(wh*2^-11)   [exact terms]
// ---------------------------------------------------------------------------
__device__ __forceinline__ void split3(float x, f16& h, f16& hs, f16& lb) {
    h = (f16)x;
    float hf = (float)h;
    hs = (f16)(hf * 4.8828125e-4f);        // *2^-11 (derived in GEMM)
    lb = (f16)((x - hf) * 2048.0f);        // residual, pre-scaled *2^11
}

// ---------------------------------------------------------------------------
// Dtype sniff, parallelized: 64-block count + 1-thread finalize.
// ---------------------------------------------------------------------------
__global__ void sniff_count_kernel(const unsigned short* __restrict__ p,
                                   int* __restrict__ cnts) {
    __shared__ int cnt;
    if (threadIdx.x == 0) cnt = 0;
    __syncthreads();
    int local = 0;
    #pragma unroll
    for (int k = 0; k < 4; ++k) {
        int i = blockIdx.x * 1024 + k * 256 + threadIdx.x;
        unsigned int bits = ((unsigned int)p[i]) << 16;
        float v = __uint_as_float(bits);
        float a = fabsf(v);
        if (!(a <= 1e4f)) local++;
        else if (v != 0.0f && a < 1e-6f) local++;
    }
    atomicAdd(&cnt, local);
    __syncthreads();
    if (threadIdx.x == 0) cnts[blockIdx.x] = cnt;
}

__global__ void sniff_final_kernel(const int* __restrict__ cnts,
                                   int* __restrict__ flag) {
    int s = 0;
    for (int i = 0; i < 64; ++i) s += cnts[i];
    *flag = (s > 1024) ? 0 : 1;
}

// ---------------------------------------------------------------------------
// Weight transpose+split: W[K][N] -> Wt ushort[N][2K]: [h | lb].
// ---------------------------------------------------------------------------
__global__ __launch_bounds__(256) void wsplit_kernel(
        const void* __restrict__ W, size_t wOff, unsigned short* __restrict__ Wt,
        int K, int N, const int* __restrict__ flag) {
    const bool isb = (*flag != 0);
    __shared__ float tile[32][33];
    const int n0 = blockIdx.x * 32, k0 = blockIdx.y * 32;
    const int t = threadIdx.x;
    {
        int lk = t >> 3, ln0 = (t & 7) << 2;
        float4 v = load4(W, wOff + (size_t)(k0 + lk) * N + n0 + ln0, isb);
        tile[lk][ln0 + 0] = v.x; tile[lk][ln0 + 1] = v.y;
        tile[lk][ln0 + 2] = v.z; tile[lk][ln0 + 3] = v.w;
    }
    __syncthreads();
    int n = t >> 3, kq0 = (t & 7) << 2;
    size_t base = (size_t)(n0 + n) * (2 * (size_t)K) + k0 + kq0;
    #pragma unroll
    for (int j = 0; j < 4; ++j) {
        float x = tile[kq0 + j][n];
        f16 h, hs, lb;
        split3(x, h, hs, lb);
        Wt[base + j]     = *(unsigned short*)&h;
        Wt[base + j + K] = *(unsigned short*)&lb;
    }
}

// ---------------------------------------------------------------------------
// GEMM1 (3-plane), 512 threads = 8 waves (4x2), wave-tile 32x64, 128x128
// tile, single-buffer 32 KB LDS, 2 barriers/ktile. The 8-wave block doubles
// the latency-hiding pool per barrier vs the 4-wave version (R17: occupancy
// 23% ~= 7.4 waves/CU). Staged LDS contents, slot swizzle ((pl<<2)|kq)^row,
// fragment reads, and per-output MFMA sequence (p0,p1,p2 per ktile asc) are
// IDENTICAL to R15/R17 -> bit-identical output. acc 2x4 (32 VGPR) keeps
// peak regs ~120: no spill at launch_bounds(512,2).
// ---------------------------------------------------------------------------
__global__ __launch_bounds__(512, 2) void gemm_mfma3_kernel(
        const unsigned short* __restrict__ At, const unsigned short* __restrict__ Wt,
        const void* __restrict__ bias, size_t bOff,
        float* __restrict__ C, int N, int K, const int* __restrict__ flag) {
    const bool isb = (*flag != 0);
    __shared__ unsigned short As[128 * 64];      // 16 KB (2 planes)
    __shared__ unsigned short Bs[128 * 64];      // 16 KB (2 planes)

    const int gx = N >> 7;
    const int gy = (int)gridDim.x / gx;
    int bx, by;
    {
        int bid = blockIdx.x;
        if ((gy & 7) == 0) {
            int k = bid & 7, i = bid >> 3;
            bx = i % gx;
            by = (gy >> 3) * k + i / gx;
        } else { bx = bid % gx; by = bid / gx; }
    }
    const int bn = bx * 128;
    const int bm = by * 128;

    const int tid  = threadIdx.x;
    const int lane = tid & 63;
    const int wave = tid >> 6;         // 0..7
    const int wm = wave >> 1;          // 0..3 : 32-row block
    const int wn = wave & 1;           // 0..1 : 64-col block
    const int g  = lane >> 4;          // k-group 0..3
    const int lr = lane & 15;

    const int sar = tid >> 2;          // 0..127 : A/B row
    const int skq = tid & 3;           // k-chunk 0..3 (8 ushorts each)

    const f16 C11 = (f16)4.8828125e-4f;   // 2^-11
    const f16x8 c11v = {C11, C11, C11, C11, C11, C11, C11, C11};

    f32x4 acc[2][4];
    #pragma unroll
    for (int i = 0; i < 2; ++i)
        #pragma unroll
        for (int j = 0; j < 4; ++j) acc[i][j] = (f32x4){0.f, 0.f, 0.f, 0.f};

    const unsigned short* Ap = At + (size_t)(bm + sar) * (2 * (size_t)K) + skq * 8;
    const unsigned short* Wp = Wt + (size_t)(bn + sar) * (2 * (size_t)K) + skq * 8;

    // prologue: prefetch tile 0 (both planes of this thread's chunk)
    f16x8 av0 = *(const f16x8*)(Ap);
    f16x8 av1 = *(const f16x8*)(Ap + K);
    f16x8 wv0 = *(const f16x8*)(Wp);
    f16x8 wv1 = *(const f16x8*)(Wp + K);

    const int nt = K >> 5;
    for (int t = 0; t < nt; ++t) {
        // ---- store staged regs to LDS (identical slot map) ----
        const int arb = sar * 64, asw = sar & 7;
        *(f16x8*)&As[arb + ((skq ^ asw)) * 8]       = av0;   // plane 0
        *(f16x8*)&As[arb + (((4 | skq) ^ asw)) * 8] = av1;   // plane 1
        *(f16x8*)&Bs[arb + ((skq ^ asw)) * 8]       = wv0;
        *(f16x8*)&Bs[arb + (((4 | skq) ^ asw)) * 8] = wv1;
        __syncthreads();
        // ---- prefetch next tile (hides under MFMAs) ----
        if (t + 1 < nt) {
            const int k0 = (t + 1) << 5;
            av0 = *(const f16x8*)(Ap + k0);
            av1 = *(const f16x8*)(Ap + K + k0);
            wv0 = *(const f16x8*)(Wp + k0);
            wv1 = *(const f16x8*)(Wp + K + k0);
        }
        // ---- fragments ----
        f16x8 a0[2], a2[2], b0[4], b2[4];
        #pragma unroll
        for (int mi = 0; mi < 2; ++mi) {
            const int ar = wm * 32 + mi * 16 + lr;
            a0[mi] = *(const f16x8*)&As[ar * 64 + ((g ^ (ar & 7))) * 8];
            a2[mi] = *(const f16x8*)&As[ar * 64 + (((4 | g) ^ (ar & 7))) * 8];
        }
        #pragma unroll
        for (int ni = 0; ni < 4; ++ni) {
            const int br = wn * 64 + ni * 16 + lr;
            b0[ni] = *(const f16x8*)&Bs[br * 64 + ((g ^ (br & 7))) * 8];
            b2[ni] = *(const f16x8*)&Bs[br * 64 + (((4 | g) ^ (br & 7))) * 8];
        }
        // ---- p0: h*wh ----
        #pragma unroll
        for (int mi = 0; mi < 2; ++mi)
            #pragma unroll
            for (int ni = 0; ni < 4; ++ni)
                acc[mi][ni] = __builtin_amdgcn_mfma_f32_16x16x32_f16(
                    a0[mi], b0[ni], acc[mi][ni], 0, 0, 0);
        // ---- p1: (h*2^-11)*(wl*2^11) ----
        {
            f16x8 a1[2];
            #pragma unroll
            for (int mi = 0; mi < 2; ++mi) a1[mi] = a0[mi] * c11v;
            #pragma unroll
            for (int mi = 0; mi < 2; ++mi)
                #pragma unroll
                for (int ni = 0; ni < 4; ++ni)
                    acc[mi][ni] = __builtin_amdgcn_mfma_f32_16x16x32_f16(
                        a1[mi], b2[ni], acc[mi][ni], 0, 0, 0);
        }
        // ---- p2: (l*2^11)*(wh*2^-11) ----
        {
            f16x8 b1[4];
            #pragma unroll
            for (int ni = 0; ni < 4; ++ni) b1[ni] = b0[ni] * c11v;
            #pragma unroll
            for (int mi = 0; mi < 2; ++mi)
                #pragma unroll
                for (int ni = 0; ni < 4; ++ni)
                    acc[mi][ni] = __builtin_amdgcn_mfma_f32_16x16x32_f16(
                        a2[mi], b1[ni], acc[mi][ni], 0, 0, 0);
        }
        __syncthreads();     // WAR: same buffer reused next ktile
    }
    // ---- epilogue: C/D map col=lane&15, row=(lane>>4)*4+reg ----
    #pragma unroll
    for (int ni = 0; ni < 4; ++ni) {
        const int col = bn + wn * 64 + ni * 16 + lr;
        const float bv = load1(bias, bOff + col, isb);
        #pragma unroll
        for (int mi = 0; mi < 2; ++mi) {
            #pragma unroll
            for (int r = 0; r < 4; ++r) {
                const size_t row = (size_t)(bm + wm * 32 + mi * 16 + g * 4 + r);
                C[row * N + col] = acc[mi][ni][r] + bv;
            }
        }
    }
}

// ---------------------------------------------------------------------------
// GEMM2 (2-plane, A = {0,1} spikes): R16's measured-best form — 128x128,
// 4 waves 2x2, DOUBLE-buffered LDS, one barrier/ktile (grid 512 blocks is
// grid-limited to 2 blk/CU so 64 KB LDS is free; halving the 64 barrier
// drains/block won R16). Sole instantiation (no template co-compile drift).
// ---------------------------------------------------------------------------
__global__ __launch_bounds__(256, 3) void gemm_mfma2_kernel(
        const unsigned short* __restrict__ At, const unsigned short* __restrict__ Wt,
        const void* __restrict__ bias, size_t bOff,
        float* __restrict__ C, int N, int K, const int* __restrict__ flag) {
    const bool isb = (*flag != 0);
    __shared__ unsigned short As[2][128 * 64];
    __shared__ unsigned short Bs[2][128 * 64];

    const int gx = N >> 7;
    const int gy = (int)gridDim.x / gx;
    int bx, by;
    {
        int bid = blockIdx.x;
        if ((gy & 7) == 0) {
            int k = bid & 7, i = bid >> 3;
            bx = i % gx;
            by = (gy >> 3) * k + i / gx;
        } else { bx = bid % gx; by = bid / gx; }
    }
    const int bn = bx * 128;
    const int bm = by * 128;

    const int tid  = threadIdx.x;
    const int lane = tid & 63;
    const int wave = tid >> 6;
    const int wm = wave >> 1;
    const int wn = wave & 1;
    const int g  = lane >> 4;
    const int lr = lane & 15;

    const int sar = tid >> 1;          // A row 0..127
    const int sah = tid & 1;           // A k-half
    const int sbn = tid >> 1;          // B n-row 0..127
    const int sq  = tid & 1;           // B k-half

    const f16 C11 = (f16)4.8828125e-4f;
    const f16x8 c11v = {C11, C11, C11, C11, C11, C11, C11, C11};

    f32x4 acc[4][4];
    #pragma unroll
    for (int i = 0; i < 4; ++i)
        #pragma unroll
        for (int j = 0; j < 4; ++j) acc[i][j] = (f32x4){0.f, 0.f, 0.f, 0.f};

    const unsigned short* Ap = At + (size_t)(bm + sar) * (size_t)K + sah * 16;
    const unsigned short* Wp = Wt + (size_t)(bn + sbn) * (2 * (size_t)K) + sq * 16;

    f16x8 av[2], wv[4];
    #pragma unroll
    for (int c = 0; c < 2; ++c)
        av[c] = *(const f16x8*)(Ap + c * 8);
    #pragma unroll
    for (int pl = 0; pl < 2; ++pl)
        #pragma unroll
        for (int c = 0; c < 2; ++c)
            wv[pl * 2 + c] = *(const f16x8*)(Wp + (size_t)pl * K + c * 8);

    const int nt = K >> 5;
    for (int t = 0; t < nt; ++t) {
        const int cur = t & 1;
        const int arb = sar * 64, asw = sar & 7;
        #pragma unroll
        for (int c = 0; c < 2; ++c) {
            const int gg = sah * 2 + c;
            *(f16x8*)&As[cur][arb + ((gg ^ asw)) * 8] = av[c];
        }
        const int brb = sbn * 64, bsw = sbn & 7;
        #pragma unroll
        for (int pl = 0; pl < 2; ++pl)
            #pragma unroll
            for (int c = 0; c < 2; ++c) {
                const int gg = sq * 2 + c;
                *(f16x8*)&Bs[cur][brb + (((pl << 2) | gg) ^ bsw) * 8] = wv[pl * 2 + c];
            }
        __syncthreads();
        if (t + 1 < nt) {
            const int k0 = (t + 1) << 5;
            #pragma unroll
            for (int c = 0; c < 2; ++c)
                av[c] = *(const f16x8*)(Ap + k0 + c * 8);
            #pragma unroll
            for (int pl = 0; pl < 2; ++pl)
                #pragma unroll
                for (int c = 0; c < 2; ++c)
                    wv[pl * 2 + c] = *(const f16x8*)(Wp + (size_t)pl * K + k0 + c * 8);
        }
        f16x8 a0[4], b0[4], b2[4];
        #pragma unroll
        for (int mi = 0; mi < 4; ++mi) {
            const int ar = wm * 64 + mi * 16 + lr;
            a0[mi] = *(const f16x8*)&As[cur][ar * 64 + ((g ^ (ar & 7))) * 8];
        }
        #pragma unroll
        for (int ni = 0; ni < 4; ++ni) {
            const int br = wn * 64 + ni * 16 + lr;
            b0[ni] = *(const f16x8*)&Bs[cur][br * 64 + ((g ^ (br & 7))) * 8];
            b2[ni] = *(const f16x8*)&Bs[cur][br * 64 + (((4 | g) ^ (br & 7))) * 8];
        }
        #pragma unroll
        for (int mi = 0; mi < 4; ++mi)
            #pragma unroll
            for (int ni = 0; ni < 4; ++ni)
                acc[mi][ni] = __builtin_amdgcn_mfma_f32_16x16x32_f16(
                    a0[mi], b0[ni], acc[mi][ni], 0, 0, 0);
        {
            f16x8 a1[4];
            #pragma unroll
            for (int mi = 0; mi < 4; ++mi) a1[mi] = a0[mi] * c11v;
            #pragma unroll
            for (int mi = 0; mi < 4; ++mi)
                #pragma unroll
                for (int ni = 0; ni < 4; ++ni)
                    acc[mi][ni] = __builtin_amdgcn_mfma_f32_16x16x32_f16(
                        a1[mi], b2[ni], acc[mi][ni], 0, 0, 0);
        }
        // no trailing barrier: next store goes to the alternate buffer
    }
    #pragma unroll
    for (int ni = 0; ni < 4; ++ni) {
        const int col = bn + wn * 64 + ni * 16 + lr;
        const float bv = load1(bias, bOff + col, isb);
        #pragma unroll
        for (int mi = 0; mi < 4; ++mi) {
            #pragma unroll
            for (int r = 0; r < 4; ++r) {
                const size_t row = (size_t)(bm + wm * 64 + mi * 16 + g * 4 + r);
                C[row * N + col] = acc[mi][ni][r] + bv;
            }
        }
    }
}

// ---------------------------------------------------------------------------
// Projector: 16 rows/block, loop-swapped phase2; emits Xc fp32 + {h,lb}
// split into At1 (row-major planes at +0 / +E_).
// ---------------------------------------------------------------------------
#define RB_ 16
__global__ __launch_bounds__(256) void proj_kernel(
        const void* __restrict__ hist, const void* __restrict__ pW1,
        const void* __restrict__ pb1,  const void* __restrict__ pW2,
        const void* __restrict__ pb2,  float* __restrict__ Xc,
        unsigned short* __restrict__ At1,
        size_t m0, const int* __restrict__ flag) {
    const bool isb = (*flag != 0);
    __shared__ float h1[RB_][HP_];
    const size_t mb = (size_t)blockIdx.x * RB_;
    const int tid = threadIdx.x;
    const int lane = tid & 63;
    const int grp = tid >> 6;
    #pragma unroll
    for (int rep = 0; rep < 4; ++rep) {
        int idx = tid + rep * 256;
        int r = idx >> 6, c = idx & 63;
        size_t gm = m0 + mb + r;
        float acc = 0.f;
        #pragma unroll
        for (int i = 0; i < IN_; ++i)
            acc = fmaf(load1(hist, gm * IN_ + i, isb),
                       load1(pW1, (size_t)i * HP_ + c, isb), acc);
        acc += load1(pb1, c, isb);
        h1[r][c] = 0.5f * acc * (1.0f + erff(acc * 0.70710678118654752440f));
    }
    __syncthreads();
    const int e0 = lane * 8;
    float acc[4][8];
    #pragma unroll
    for (int r = 0; r < 4; ++r)
        #pragma unroll
        for (int j = 0; j < 8; ++j) acc[r][j] = 0.f;
    for (int i = 0; i < HP_; ++i) {
        float4 wA = load4(pW2, (size_t)i * E_ + e0, isb);
        float4 wB = load4(pW2, (size_t)i * E_ + e0 + 4, isb);
        float w[8] = {wA.x, wA.y, wA.z, wA.w, wB.x, wB.y, wB.z, wB.w};
        #pragma unroll
        for (int r = 0; r < 4; ++r) {
            float h = h1[grp * 4 + r][i];
            #pragma unroll
            for (int j = 0; j < 8; ++j) acc[r][j] = fmaf(h, w[j], acc[r][j]);
        }
    }
    #pragma unroll
    for (int r = 0; r < 4; ++r) {
        size_t row = mb + grp * 4 + r;
        float o[8];
        #pragma unroll
        for (int j = 0; j < 8; ++j)
            o[j] = acc[r][j] + load1(pb2, e0 + j, isb);
        *(float4*)(Xc + row * E_ + e0)     = (float4){o[0], o[1], o[2], o[3]};
        *(float4*)(Xc + row * E_ + e0 + 4) = (float4){o[4], o[5], o[6], o[7]};
        f16x8 hv, lv;
        #pragma unroll
        for (int j = 0; j < 8; ++j) {
            f16 h, hs, lb;
            split3(o[j], h, hs, lb);
            hv[j] = h; lv[j] = lb;
        }
        *(f16x8*)&At1[row * (2 * E_) + e0]      = hv;
        *(f16x8*)&At1[row * (2 * E_) + E_ + e0] = lv;
    }
}

// ---------------------------------------------------------------------------
// LayerNorm stats only: same block_sum tree -> bit-identical mean/denom.
// ---------------------------------------------------------------------------
__device__ __forceinline__ float block_sum(float v, float* smem, int tid) {
    #pragma unroll
    for (int off = 32; off > 0; off >>= 1) v += __shfl_down(v, off, 64);
    __syncthreads();
    if ((tid & 63) == 0) smem[tid >> 6] = v;
    __syncthreads();
    if (tid == 0) smem[4] = smem[0] + smem[1] + smem[2] + smem[3];
    __syncthreads();
    return smem[4];
}

__global__ __launch_bounds__(256) void ln_stats_kernel(const float* __restrict__ Y,
                                                       float* __restrict__ stats,
                                                       int N) {
    __shared__ float smem[5];
    size_t row = blockIdx.x;
    const float* y = Y + row * (size_t)N;
    int tid = threadIdx.x;
    int nPer = N >> 8;
    float vals[4];
    float s = 0.f;
    for (int i = 0; i < nPer; ++i) { float v = y[tid + (i << 8)]; vals[i] = v; s += v; }
    float mean = block_sum(s, smem, tid) / (float)N;
    float sq = 0.f;
    for (int i = 0; i < nPer; ++i) { float d0 = vals[i] - mean; sq += d0 * d0; }
    float var = block_sum(sq, smem, tid) / (float)N;
    if (tid == 0) {
        stats[row * 2]     = mean;
        stats[row * 2 + 1] = sqrtf(var + 1e-5f);
    }
}

// ---------------------------------------------------------------------------
// LIF scan with fused LN-apply, x16 software pipeline.
// ---------------------------------------------------------------------------
__global__ __launch_bounds__(64) void lif_kernel(const float* __restrict__ Y,
                                                 const float* __restrict__ stats,
                                                 const void* __restrict__ g, size_t gOff,
                                                 const void* __restrict__ b, size_t bOff,
                                                 unsigned short* __restrict__ At2,
                                                 int N, const int* __restrict__ flag) {
    const bool isb = (*flag != 0);
    int f = blockIdx.x * 64 + threadIdx.x;
    int bb = blockIdx.y;
    const float gw = load1(g, gOff + f, isb);
    const float bw = load1(b, bOff + f, isb);
    size_t base = (size_t)bb * T_ * N + f;
    size_t srow = (size_t)bb * T_;
    float v = 0.f;
    for (int t0 = 0; t0 < T_; t0 += 16) {
        float x[16], mn[16], dn[16], s[16];
        #pragma unroll
        for (int j = 0; j < 16; ++j) {
            x[j]  = Y[base + (size_t)(t0 + j) * N];
            mn[j] = stats[(srow + t0 + j) * 2];
            dn[j] = stats[(srow + t0 + j) * 2 + 1];
        }
        #pragma unroll
        for (int j = 0; j < 16; ++j) {
            float xn = (x[j] - mn[j]) / dn[j] * gw + bw;
            v = v + (xn - v) * 0.5f;
            s[j] = (v - 1.0f >= 0.0f) ? 1.0f : 0.0f;
            v = v * (1.0f - s[j]);
        }
        #pragma unroll
        for (int j = 0; j < 16; ++j) {
            f16 h = (f16)s[j];
            At2[base + (size_t)(t0 + j) * N] = *(unsigned short*)&h;
        }
    }
}

// Second LIF: fused LN-apply + residual add into Xc + {h,lb} split to At1.
// When lastLayer!=0 also writes the t=T-1 value to the final output.
__global__ __launch_bounds__(64) void lif_add_kernel(const float* __restrict__ Z,
                                                     const float* __restrict__ stats,
                                                     const void* __restrict__ g, size_t gOff,
                                                     const void* __restrict__ b, size_t bOff,
                                                     float* __restrict__ Xc,
                                                     unsigned short* __restrict__ At1,
                                                     void* __restrict__ outp, int b0,
                                                     int lastLayer,
                                                     const int* __restrict__ flag) {
    const bool isb = (*flag != 0);
    int e = blockIdx.x * 64 + threadIdx.x;
    int bb = blockIdx.y;
    const float gw = load1(g, gOff + e, isb);
    const float bw = load1(b, bOff + e, isb);
    size_t base  = (size_t)bb * T_ * E_ + e;
    size_t base2 = (size_t)bb * T_ * (2 * E_) + e;
    size_t srow  = (size_t)bb * T_;
    float v = 0.f;
    for (int t0 = 0; t0 < T_; t0 += 16) {
        float x[16], xc[16], mn[16], dn[16], s[16];
        #pragma unroll
        for (int j = 0; j < 16; ++j) {
            x[j]  = Z[base + (size_t)(t0 + j) * E_];
            mn[j] = stats[(srow + t0 + j) * 2];
            dn[j] = stats[(srow + t0 + j) * 2 + 1];
        }
        #pragma unroll
        for (int j = 0; j < 16; ++j) xc[j] = Xc[base + (size_t)(t0 + j) * E_];
        #pragma unroll
        for (int j = 0; j < 16; ++j) {
            float xn = (x[j] - mn[j]) / dn[j] * gw + bw;
            v = v + (xn - v) * 0.5f;
            s[j] = (v - 1.0f >= 0.0f) ? 1.0f : 0.0f;
            v = v * (1.0f - s[j]);
        }
        #pragma unroll
        for (int j = 0; j < 16; ++j) {
            float nx = xc[j] + s[j];
            Xc[base + (size_t)(t0 + j) * E_] = nx;
            f16 h, hs, lb;
            split3(nx, h, hs, lb);
            At1[base2 + (size_t)(t0 + j) * (2 * E_)]      = *(unsigned short*)&h;
            At1[base2 + (size_t)(t0 + j) * (2 * E_) + E_] = *(unsigned short*)&lb;
        }
        if (lastLayer && t0 + 16 == T_) {
            float nx = Xc[base + (size_t)(T_ - 1) * E_];
            size_t oi = (size_t)(b0 + bb) * E_ + e;
            if (isb) ((bf16*)outp)[oi] = __float2bfloat16(nx);
            else     ((float*)outp)[oi] = nx;
        }
    }
}

// ---------------------------------------------------------------------------
extern "C" void kernel_launch(void* const* d_in, const int* in_sizes, int n_in,
                              void* d_out, int out_size, void* d_ws, size_t ws_size,
                              hipStream_t stream) {
    char* ws = (char*)d_ws;
    int* flag = (int*)ws;
    int* cnts = (int*)(ws + 64);      // 64 ints, header is 512 B total

    const size_t wtCount = 2 * (size_t)E_ * H_;
    const size_t wtBytes = 2 * D_ * wtCount * sizeof(unsigned short); // ~16.8 MB
    unsigned short* Wt1 = (unsigned short*)(ws + 512);
    unsigned short* Wt2 = Wt1 + (size_t)D_ * wtCount;

    size_t used = 512 + wtBytes;
    size_t avail = (ws_size > used) ? ws_size - used : 0;
    // per batch: fp32 bufs + At1 + At2 + stats (2 bufs x 2 floats/row)
    const size_t perBatch = (size_t)T_ * ((E_ + H_ + E_) * 4 + 2 * E_ * 2 + H_ * 2 + 16);
    int CB = 256;
    while (CB > 1 && (size_t)CB * perBatch > avail) CB >>= 1;
    const int R = CB * T_;

    float* Xc  = (float*)(ws + used);
    float* HBc = Xc + (size_t)R * E_;
    float* Y2c = HBc + (size_t)R * H_;
    unsigned short* At1 = (unsigned short*)(Y2c + (size_t)R * E_);
    unsigned short* At2 = At1 + (size_t)R * 2 * E_;
    float* St1 = (float*)(At2 + (size_t)R * H_);
    float* St2 = St1 + (size_t)R * 2;

    sniff_count_kernel<<<64, 256, 0, stream>>>((const unsigned short*)d_in[0], cnts);
    sniff_final_kernel<<<1, 1, 0, stream>>>(cnts, flag);

    for (int d = 0; d < D_; ++d) {
        wsplit_kernel<<<dim3(H_ / 32, E_ / 32), 256, 0, stream>>>(
            d_in[5], (size_t)d * E_ * H_, Wt1 + (size_t)d * wtCount, E_, H_, flag);
        wsplit_kernel<<<dim3(E_ / 32, H_ / 32), 256, 0, stream>>>(
            d_in[9], (size_t)d * H_ * E_, Wt2 + (size_t)d * wtCount, H_, E_, flag);
    }

    for (int b0 = 0; b0 < B_; b0 += CB) {
        proj_kernel<<<R / RB_, 256, 0, stream>>>(d_in[0], d_in[1], d_in[2], d_in[3],
                                                 d_in[4], Xc, At1, (size_t)b0 * T_, flag);
        for (int d = 0; d < D_; ++d) {
            size_t b1o = (size_t)d * H_;
            size_t b2o = (size_t)d * E_;

            gemm_mfma3_kernel<<<(H_ / 128) * (R / 128), 512, 0, stream>>>(
                At1, Wt1 + (size_t)d * wtCount, d_in[6], b1o, HBc, H_, E_, flag);
            ln_stats_kernel<<<R, 256, 0, stream>>>(HBc, St1, H_);
            lif_kernel<<<dim3(H_ / 64, CB), 64, 0, stream>>>(
                HBc, St1, d_in[7], b1o, d_in[8], b1o, At2, H_, flag);

            gemm_mfma2_kernel<<<(E_ / 128) * (R / 128), 256, 0, stream>>>(
                At2, Wt2 + (size_t)d * wtCount, d_in[10], b2o, Y2c, E_, H_, flag);
            ln_stats_kernel<<<R, 256, 0, stream>>>(Y2c, St2, E_);
            lif_add_kernel<<<dim3(E_ / 64, CB), 64, 0, stream>>>(
                Y2c, St2, d_in[11], b2o, d_in[12], b2o, Xc, At1,
                d_out, b0, (d == D_ - 1) ? 1 : 0, flag);
        }
    }
}

// Round 20
// 2950.921 us; speedup vs baseline: 1.1646x; 1.1646x over previous
//
#include <hip/hip_runtime.h>
#include <hip/hip_bf16.h>
#include <math.h>

#define B_  256
#define T_  256
#define IN_ 4
#define HP_ 64
#define E_  512
#define H_  1024
#define D_  4

typedef __hip_bfloat16 bf16;
typedef _Float16 f16;
typedef _Float16 f16x8 __attribute__((ext_vector_type(8)));
typedef float f32x4 __attribute__((ext_vector_type(4)));

// ---------------------------------------------------------------------------
// Dual-dtype load helpers: flag!=0 -> input arrays are bf16, else fp32.
// ---------------------------------------------------------------------------
__device__ __forceinline__ float load1(const void* p, size_t idx, bool isb) {
    if (isb) {
        unsigned int u = ((const unsigned short*)p)[idx];
        return __uint_as_float(u << 16);
    }
    return ((const float*)p)[idx];
}

__device__ __forceinline__ float4 load4(const void* p, size_t idx, bool isb) {
    if (isb) {
        ushort4 u = *(const ushort4*)((const unsigned short*)p + idx);
        float4 r;
        r.x = __uint_as_float(((unsigned int)u.x) << 16);
        r.y = __uint_as_float(((unsigned int)u.y) << 16);
        r.z = __uint_as_float(((unsigned int)u.z) << 16);
        r.w = __uint_as_float(((unsigned int)u.w) << 16);
        return r;
    }
    return *((const float4*)p + (idx >> 2));
}

// ---------------------------------------------------------------------------
// Exact 3-plane f16 split:  x ~= h + lb*2^-11  (lb pre-scaled by 2^11).
// x*w = h*wh + (h*2^-11)*(wl*2^11) + (l*2^11)*(wh*2^-11)   [exact terms]
// ---------------------------------------------------------------------------
__device__ __forceinline__ void split3(float x, f16& h, f16& hs, f16& lb) {
    h = (f16)x;
    float hf = (float)h;
    hs = (f16)(hf * 4.8828125e-4f);        // *2^-11 (derived in GEMM)
    lb = (f16)((x - hf) * 2048.0f);        // residual, pre-scaled *2^11
}

// ---------------------------------------------------------------------------
// Dtype sniff, parallelized: 64-block count + 1-thread finalize.
// ---------------------------------------------------------------------------
__global__ void sniff_count_kernel(const unsigned short* __restrict__ p,
                                   int* __restrict__ cnts) {
    __shared__ int cnt;
    if (threadIdx.x == 0) cnt = 0;
    __syncthreads();
    int local = 0;
    #pragma unroll
    for (int k = 0; k < 4; ++k) {
        int i = blockIdx.x * 1024 + k * 256 + threadIdx.x;
        unsigned int bits = ((unsigned int)p[i]) << 16;
        float v = __uint_as_float(bits);
        float a = fabsf(v);
        if (!(a <= 1e4f)) local++;
        else if (v != 0.0f && a < 1e-6f) local++;
    }
    atomicAdd(&cnt, local);
    __syncthreads();
    if (threadIdx.x == 0) cnts[blockIdx.x] = cnt;
}

__global__ void sniff_final_kernel(const int* __restrict__ cnts,
                                   int* __restrict__ flag) {
    int s = 0;
    for (int i = 0; i < 64; ++i) s += cnts[i];
    *flag = (s > 1024) ? 0 : 1;
}

// ---------------------------------------------------------------------------
// Weight transpose+split: W[K][N] -> Wt ushort[N][2K]: [h | lb].
// ---------------------------------------------------------------------------
__global__ __launch_bounds__(256) void wsplit_kernel(
        const void* __restrict__ W, size_t wOff, unsigned short* __restrict__ Wt,
        int K, int N, const int* __restrict__ flag) {
    const bool isb = (*flag != 0);
    __shared__ float tile[32][33];
    const int n0 = blockIdx.x * 32, k0 = blockIdx.y * 32;
    const int t = threadIdx.x;
    {
        int lk = t >> 3, ln0 = (t & 7) << 2;
        float4 v = load4(W, wOff + (size_t)(k0 + lk) * N + n0 + ln0, isb);
        tile[lk][ln0 + 0] = v.x; tile[lk][ln0 + 1] = v.y;
        tile[lk][ln0 + 2] = v.z; tile[lk][ln0 + 3] = v.w;
    }
    __syncthreads();
    int n = t >> 3, kq0 = (t & 7) << 2;
    size_t base = (size_t)(n0 + n) * (2 * (size_t)K) + k0 + kq0;
    #pragma unroll
    for (int j = 0; j < 4; ++j) {
        float x = tile[kq0 + j][n];
        f16 h, hs, lb;
        split3(x, h, hs, lb);
        Wt[base + j]     = *(unsigned short*)&h;
        Wt[base + j + K] = *(unsigned short*)&lb;
    }
}

// ---------------------------------------------------------------------------
// LN partial finalize: per row, sum block partials in FIXED slot order
// (deterministic), mean = S/N, var = S2/N - mean^2 (>=0 guard).
// Perturbs mean/denom ~1e-7 rel vs the old two-pass tree — same magnitude
// class as the accepted fp32->split3 transition (absmax stayed 0.0).
// ---------------------------------------------------------------------------
__global__ __launch_bounds__(256) void ln_fin_kernel(const float* __restrict__ P,
                                                     int ns, float* __restrict__ stats,
                                                     int N) {
    int row = blockIdx.x * 256 + threadIdx.x;
    const float* p = P + (size_t)row * ns * 2;
    float s = 0.f, s2 = 0.f;
    for (int i = 0; i < ns; ++i) {
        s  += p[i * 2];
        s2 += p[i * 2 + 1];
    }
    float mean = s / (float)N;
    float var  = fmaxf(s2 / (float)N - mean * mean, 0.f);
    stats[row * 2]     = mean;
    stats[row * 2 + 1] = sqrtf(var + 1e-5f);
}

// ---------------------------------------------------------------------------
// GEMM1 (3-plane), 512 threads = 8 waves (4x2), wave-tile 32x64, 128x128
// tile, single-buffer 32 KB LDS, 2 barriers/ktile (R18-measured best form).
// Epilogue additionally reduces each row's 64-col slice (ni asc in-thread,
// then a fixed 4-step shuffle tree over the 16-lane group) and writes
// {sum, sumsq} partials to Pt[row][bx*2+wn] — feeding ln_fin, which
// replaces the ln_stats full re-read of C.
// ---------------------------------------------------------------------------
__global__ __launch_bounds__(512, 2) void gemm_mfma3_kernel(
        const unsigned short* __restrict__ At, const unsigned short* __restrict__ Wt,
        const void* __restrict__ bias, size_t bOff,
        float* __restrict__ C, float* __restrict__ Pt,
        int N, int K, const int* __restrict__ flag) {
    const bool isb = (*flag != 0);
    __shared__ unsigned short As[128 * 64];      // 16 KB (2 planes)
    __shared__ unsigned short Bs[128 * 64];      // 16 KB (2 planes)

    const int gx = N >> 7;
    const int gy = (int)gridDim.x / gx;
    int bx, by;
    {
        int bid = blockIdx.x;
        if ((gy & 7) == 0) {
            int k = bid & 7, i = bid >> 3;
            bx = i % gx;
            by = (gy >> 3) * k + i / gx;
        } else { bx = bid % gx; by = bid / gx; }
    }
    const int bn = bx * 128;
    const int bm = by * 128;

    const int tid  = threadIdx.x;
    const int lane = tid & 63;
    const int wave = tid >> 6;         // 0..7
    const int wm = wave >> 1;          // 0..3 : 32-row block
    const int wn = wave & 1;           // 0..1 : 64-col block
    const int g  = lane >> 4;          // k-group 0..3
    const int lr = lane & 15;

    const int sar = tid >> 2;          // 0..127 : A/B row
    const int skq = tid & 3;           // k-chunk 0..3 (8 ushorts each)

    const f16 C11 = (f16)4.8828125e-4f;   // 2^-11
    const f16x8 c11v = {C11, C11, C11, C11, C11, C11, C11, C11};

    f32x4 acc[2][4];
    #pragma unroll
    for (int i = 0; i < 2; ++i)
        #pragma unroll
        for (int j = 0; j < 4; ++j) acc[i][j] = (f32x4){0.f, 0.f, 0.f, 0.f};

    const unsigned short* Ap = At + (size_t)(bm + sar) * (2 * (size_t)K) + skq * 8;
    const unsigned short* Wp = Wt + (size_t)(bn + sar) * (2 * (size_t)K) + skq * 8;

    f16x8 av0 = *(const f16x8*)(Ap);
    f16x8 av1 = *(const f16x8*)(Ap + K);
    f16x8 wv0 = *(const f16x8*)(Wp);
    f16x8 wv1 = *(const f16x8*)(Wp + K);

    const int nt = K >> 5;
    for (int t = 0; t < nt; ++t) {
        const int arb = sar * 64, asw = sar & 7;
        *(f16x8*)&As[arb + ((skq ^ asw)) * 8]       = av0;
        *(f16x8*)&As[arb + (((4 | skq) ^ asw)) * 8] = av1;
        *(f16x8*)&Bs[arb + ((skq ^ asw)) * 8]       = wv0;
        *(f16x8*)&Bs[arb + (((4 | skq) ^ asw)) * 8] = wv1;
        __syncthreads();
        if (t + 1 < nt) {
            const int k0 = (t + 1) << 5;
            av0 = *(const f16x8*)(Ap + k0);
            av1 = *(const f16x8*)(Ap + K + k0);
            wv0 = *(const f16x8*)(Wp + k0);
            wv1 = *(const f16x8*)(Wp + K + k0);
        }
        f16x8 a0[2], a2[2], b0[4], b2[4];
        #pragma unroll
        for (int mi = 0; mi < 2; ++mi) {
            const int ar = wm * 32 + mi * 16 + lr;
            a0[mi] = *(const f16x8*)&As[ar * 64 + ((g ^ (ar & 7))) * 8];
            a2[mi] = *(const f16x8*)&As[ar * 64 + (((4 | g) ^ (ar & 7))) * 8];
        }
        #pragma unroll
        for (int ni = 0; ni < 4; ++ni) {
            const int br = wn * 64 + ni * 16 + lr;
            b0[ni] = *(const f16x8*)&Bs[br * 64 + ((g ^ (br & 7))) * 8];
            b2[ni] = *(const f16x8*)&Bs[br * 64 + (((4 | g) ^ (br & 7))) * 8];
        }
        #pragma unroll
        for (int mi = 0; mi < 2; ++mi)
            #pragma unroll
            for (int ni = 0; ni < 4; ++ni)
                acc[mi][ni] = __builtin_amdgcn_mfma_f32_16x16x32_f16(
                    a0[mi], b0[ni], acc[mi][ni], 0, 0, 0);
        {
            f16x8 a1[2];
            #pragma unroll
            for (int mi = 0; mi < 2; ++mi) a1[mi] = a0[mi] * c11v;
            #pragma unroll
            for (int mi = 0; mi < 2; ++mi)
                #pragma unroll
                for (int ni = 0; ni < 4; ++ni)
                    acc[mi][ni] = __builtin_amdgcn_mfma_f32_16x16x32_f16(
                        a1[mi], b2[ni], acc[mi][ni], 0, 0, 0);
        }
        {
            f16x8 b1[4];
            #pragma unroll
            for (int ni = 0; ni < 4; ++ni) b1[ni] = b0[ni] * c11v;
            #pragma unroll
            for (int mi = 0; mi < 2; ++mi)
                #pragma unroll
                for (int ni = 0; ni < 4; ++ni)
                    acc[mi][ni] = __builtin_amdgcn_mfma_f32_16x16x32_f16(
                        a2[mi], b1[ni], acc[mi][ni], 0, 0, 0);
        }
        __syncthreads();
    }
    // ---- epilogue: store C + per-row {sum,sumsq} partials ----
    const int nslot = gx * 2;
    float bvv[4];
    #pragma unroll
    for (int ni = 0; ni < 4; ++ni)
        bvv[ni] = load1(bias, bOff + bn + wn * 64 + ni * 16 + lr, isb);
    #pragma unroll
    for (int mi = 0; mi < 2; ++mi) {
        #pragma unroll
        for (int r = 0; r < 4; ++r) {
            const size_t row = (size_t)(bm + wm * 32 + mi * 16 + g * 4 + r);
            float s = 0.f, s2 = 0.f;
            #pragma unroll
            for (int ni = 0; ni < 4; ++ni) {
                const int col = bn + wn * 64 + ni * 16 + lr;
                float o = acc[mi][ni][r] + bvv[ni];
                C[row * N + col] = o;
                s += o; s2 = fmaf(o, o, s2);
            }
            #pragma unroll
            for (int off = 1; off < 16; off <<= 1) {
                s  += __shfl_xor(s,  off, 64);
                s2 += __shfl_xor(s2, off, 64);
            }
            if (lr == 0) {
                const int slot = bx * 2 + wn;
                Pt[row * (size_t)(2 * nslot) + slot * 2]     = s;
                Pt[row * (size_t)(2 * nslot) + slot * 2 + 1] = s2;
            }
        }
    }
}

// ---------------------------------------------------------------------------
// GEMM2 (2-plane, A = {0,1} spikes): R16-measured-best — 128x128, 4 waves
// 2x2, DOUBLE-buffered LDS, one barrier/ktile. Epilogue emits row partials
// like GEMM1.
// ---------------------------------------------------------------------------
__global__ __launch_bounds__(256, 3) void gemm_mfma2_kernel(
        const unsigned short* __restrict__ At, const unsigned short* __restrict__ Wt,
        const void* __restrict__ bias, size_t bOff,
        float* __restrict__ C, float* __restrict__ Pt,
        int N, int K, const int* __restrict__ flag) {
    const bool isb = (*flag != 0);
    __shared__ unsigned short As[2][128 * 64];
    __shared__ unsigned short Bs[2][128 * 64];

    const int gx = N >> 7;
    const int gy = (int)gridDim.x / gx;
    int bx, by;
    {
        int bid = blockIdx.x;
        if ((gy & 7) == 0) {
            int k = bid & 7, i = bid >> 3;
            bx = i % gx;
            by = (gy >> 3) * k + i / gx;
        } else { bx = bid % gx; by = bid / gx; }
    }
    const int bn = bx * 128;
    const int bm = by * 128;

    const int tid  = threadIdx.x;
    const int lane = tid & 63;
    const int wave = tid >> 6;
    const int wm = wave >> 1;
    const int wn = wave & 1;
    const int g  = lane >> 4;
    const int lr = lane & 15;

    const int sar = tid >> 1;          // A row 0..127
    const int sah = tid & 1;           // A k-half
    const int sbn = tid >> 1;          // B n-row 0..127
    const int sq  = tid & 1;           // B k-half

    const f16 C11 = (f16)4.8828125e-4f;
    const f16x8 c11v = {C11, C11, C11, C11, C11, C11, C11, C11};

    f32x4 acc[4][4];
    #pragma unroll
    for (int i = 0; i < 4; ++i)
        #pragma unroll
        for (int j = 0; j < 4; ++j) acc[i][j] = (f32x4){0.f, 0.f, 0.f, 0.f};

    const unsigned short* Ap = At + (size_t)(bm + sar) * (size_t)K + sah * 16;
    const unsigned short* Wp = Wt + (size_t)(bn + sbn) * (2 * (size_t)K) + sq * 16;

    f16x8 av[2], wv[4];
    #pragma unroll
    for (int c = 0; c < 2; ++c)
        av[c] = *(const f16x8*)(Ap + c * 8);
    #pragma unroll
    for (int pl = 0; pl < 2; ++pl)
        #pragma unroll
        for (int c = 0; c < 2; ++c)
            wv[pl * 2 + c] = *(const f16x8*)(Wp + (size_t)pl * K + c * 8);

    const int nt = K >> 5;
    for (int t = 0; t < nt; ++t) {
        const int cur = t & 1;
        const int arb = sar * 64, asw = sar & 7;
        #pragma unroll
        for (int c = 0; c < 2; ++c) {
            const int gg = sah * 2 + c;
            *(f16x8*)&As[cur][arb + ((gg ^ asw)) * 8] = av[c];
        }
        const int brb = sbn * 64, bsw = sbn & 7;
        #pragma unroll
        for (int pl = 0; pl < 2; ++pl)
            #pragma unroll
            for (int c = 0; c < 2; ++c) {
                const int gg = sq * 2 + c;
                *(f16x8*)&Bs[cur][brb + (((pl << 2) | gg) ^ bsw) * 8] = wv[pl * 2 + c];
            }
        __syncthreads();
        if (t + 1 < nt) {
            const int k0 = (t + 1) << 5;
            #pragma unroll
            for (int c = 0; c < 2; ++c)
                av[c] = *(const f16x8*)(Ap + k0 + c * 8);
            #pragma unroll
            for (int pl = 0; pl < 2; ++pl)
                #pragma unroll
                for (int c = 0; c < 2; ++c)
                    wv[pl * 2 + c] = *(const f16x8*)(Wp + (size_t)pl * K + k0 + c * 8);
        }
        f16x8 a0[4], b0[4], b2[4];
        #pragma unroll
        for (int mi = 0; mi < 4; ++mi) {
            const int ar = wm * 64 + mi * 16 + lr;
            a0[mi] = *(const f16x8*)&As[cur][ar * 64 + ((g ^ (ar & 7))) * 8];
        }
        #pragma unroll
        for (int ni = 0; ni < 4; ++ni) {
            const int br = wn * 64 + ni * 16 + lr;
            b0[ni] = *(const f16x8*)&Bs[cur][br * 64 + ((g ^ (br & 7))) * 8];
            b2[ni] = *(const f16x8*)&Bs[cur][br * 64 + (((4 | g) ^ (br & 7))) * 8];
        }
        #pragma unroll
        for (int mi = 0; mi < 4; ++mi)
            #pragma unroll
            for (int ni = 0; ni < 4; ++ni)
                acc[mi][ni] = __builtin_amdgcn_mfma_f32_16x16x32_f16(
                    a0[mi], b0[ni], acc[mi][ni], 0, 0, 0);
        {
            f16x8 a1[4];
            #pragma unroll
            for (int mi = 0; mi < 4; ++mi) a1[mi] = a0[mi] * c11v;
            #pragma unroll
            for (int mi = 0; mi < 4; ++mi)
                #pragma unroll
                for (int ni = 0; ni < 4; ++ni)
                    acc[mi][ni] = __builtin_amdgcn_mfma_f32_16x16x32_f16(
                        a1[mi], b2[ni], acc[mi][ni], 0, 0, 0);
        }
        // no trailing barrier: next store goes to the alternate buffer
    }
    // ---- epilogue: store C + per-row {sum,sumsq} partials ----
    const int nslot = gx * 2;
    float bvv[4];
    #pragma unroll
    for (int ni = 0; ni < 4; ++ni)
        bvv[ni] = load1(bias, bOff + bn + wn * 64 + ni * 16 + lr, isb);
    #pragma unroll
    for (int mi = 0; mi < 4; ++mi) {
        #pragma unroll
        for (int r = 0; r < 4; ++r) {
            const size_t row = (size_t)(bm + wm * 64 + mi * 16 + g * 4 + r);
            float s = 0.f, s2 = 0.f;
            #pragma unroll
            for (int ni = 0; ni < 4; ++ni) {
                const int col = bn + wn * 64 + ni * 16 + lr;
                float o = acc[mi][ni][r] + bvv[ni];
                C[row * N + col] = o;
                s += o; s2 = fmaf(o, o, s2);
            }
            #pragma unroll
            for (int off = 1; off < 16; off <<= 1) {
                s  += __shfl_xor(s,  off, 64);
                s2 += __shfl_xor(s2, off, 64);
            }
            if (lr == 0) {
                const int slot = bx * 2 + wn;
                Pt[row * (size_t)(2 * nslot) + slot * 2]     = s;
                Pt[row * (size_t)(2 * nslot) + slot * 2 + 1] = s2;
            }
        }
    }
}

// ---------------------------------------------------------------------------
// Projector: 16 rows/block, loop-swapped phase2; emits Xc fp32 + {h,lb}
// split into At1 (row-major planes at +0 / +E_).
// ---------------------------------------------------------------------------
#define RB_ 16
__global__ __launch_bounds__(256) void proj_kernel(
        const void* __restrict__ hist, const void* __restrict__ pW1,
        const void* __restrict__ pb1,  const void* __restrict__ pW2,
        const void* __restrict__ pb2,  float* __restrict__ Xc,
        unsigned short* __restrict__ At1,
        size_t m0, const int* __restrict__ flag) {
    const bool isb = (*flag != 0);
    __shared__ float h1[RB_][HP_];
    const size_t mb = (size_t)blockIdx.x * RB_;
    const int tid = threadIdx.x;
    const int lane = tid & 63;
    const int grp = tid >> 6;
    #pragma unroll
    for (int rep = 0; rep < 4; ++rep) {
        int idx = tid + rep * 256;
        int r = idx >> 6, c = idx & 63;
        size_t gm = m0 + mb + r;
        float acc = 0.f;
        #pragma unroll
        for (int i = 0; i < IN_; ++i)
            acc = fmaf(load1(hist, gm * IN_ + i, isb),
                       load1(pW1, (size_t)i * HP_ + c, isb), acc);
        acc += load1(pb1, c, isb);
        h1[r][c] = 0.5f * acc * (1.0f + erff(acc * 0.70710678118654752440f));
    }
    __syncthreads();
    const int e0 = lane * 8;
    float acc[4][8];
    #pragma unroll
    for (int r = 0; r < 4; ++r)
        #pragma unroll
        for (int j = 0; j < 8; ++j) acc[r][j] = 0.f;
    for (int i = 0; i < HP_; ++i) {
        float4 wA = load4(pW2, (size_t)i * E_ + e0, isb);
        float4 wB = load4(pW2, (size_t)i * E_ + e0 + 4, isb);
        float w[8] = {wA.x, wA.y, wA.z, wA.w, wB.x, wB.y, wB.z, wB.w};
        #pragma unroll
        for (int r = 0; r < 4; ++r) {
            float h = h1[grp * 4 + r][i];
            #pragma unroll
            for (int j = 0; j < 8; ++j) acc[r][j] = fmaf(h, w[j], acc[r][j]);
        }
    }
    #pragma unroll
    for (int r = 0; r < 4; ++r) {
        size_t row = mb + grp * 4 + r;
        float o[8];
        #pragma unroll
        for (int j = 0; j < 8; ++j)
            o[j] = acc[r][j] + load1(pb2, e0 + j, isb);
        *(float4*)(Xc + row * E_ + e0)     = (float4){o[0], o[1], o[2], o[3]};
        *(float4*)(Xc + row * E_ + e0 + 4) = (float4){o[4], o[5], o[6], o[7]};
        f16x8 hv, lv;
        #pragma unroll
        for (int j = 0; j < 8; ++j) {
            f16 h, hs, lb;
            split3(o[j], h, hs, lb);
            hv[j] = h; lv[j] = lb;
        }
        *(f16x8*)&At1[row * (2 * E_) + e0]      = hv;
        *(f16x8*)&At1[row * (2 * E_) + E_ + e0] = lv;
    }
}

// ---------------------------------------------------------------------------
// LIF scan with fused LN-apply, x16 software pipeline.
// ---------------------------------------------------------------------------
__global__ __launch_bounds__(64) void lif_kernel(const float* __restrict__ Y,
                                                 const float* __restrict__ stats,
                                                 const void* __restrict__ g, size_t gOff,
                                                 const void* __restrict__ b, size_t bOff,
                                                 unsigned short* __restrict__ At2,
                                                 int N, const int* __restrict__ flag) {
    const bool isb = (*flag != 0);
    int f = blockIdx.x * 64 + threadIdx.x;
    int bb = blockIdx.y;
    const float gw = load1(g, gOff + f, isb);
    const float bw = load1(b, bOff + f, isb);
    size_t base = (size_t)bb * T_ * N + f;
    size_t srow = (size_t)bb * T_;
    float v = 0.f;
    for (int t0 = 0; t0 < T_; t0 += 16) {
        float x[16], mn[16], dn[16], s[16];
        #pragma unroll
        for (int j = 0; j < 16; ++j) {
            x[j]  = Y[base + (size_t)(t0 + j) * N];
            mn[j] = stats[(srow + t0 + j) * 2];
            dn[j] = stats[(srow + t0 + j) * 2 + 1];
        }
        #pragma unroll
        for (int j = 0; j < 16; ++j) {
            float xn = (x[j] - mn[j]) / dn[j] * gw + bw;
            v = v + (xn - v) * 0.5f;
            s[j] = (v - 1.0f >= 0.0f) ? 1.0f : 0.0f;
            v = v * (1.0f - s[j]);
        }
        #pragma unroll
        for (int j = 0; j < 16; ++j) {
            f16 h = (f16)s[j];
            At2[base + (size_t)(t0 + j) * N] = *(unsigned short*)&h;
        }
    }
}

// Second LIF: fused LN-apply + residual add into Xc + {h,lb} split to At1.
// When lastLayer!=0 also writes the t=T-1 value to the final output.
__global__ __launch_bounds__(64) void lif_add_kernel(const float* __restrict__ Z,
                                                     const float* __restrict__ stats,
                                                     const void* __restrict__ g, size_t gOff,
                                                     const void* __restrict__ b, size_t bOff,
                                                     float* __restrict__ Xc,
                                                     unsigned short* __restrict__ At1,
                                                     void* __restrict__ outp, int b0,
                                                     int lastLayer,
                                                     const int* __restrict__ flag) {
    const bool isb = (*flag != 0);
    int e = blockIdx.x * 64 + threadIdx.x;
    int bb = blockIdx.y;
    const float gw = load1(g, gOff + e, isb);
    const float bw = load1(b, bOff + e, isb);
    size_t base  = (size_t)bb * T_ * E_ + e;
    size_t base2 = (size_t)bb * T_ * (2 * E_) + e;
    size_t srow  = (size_t)bb * T_;
    float v = 0.f;
    for (int t0 = 0; t0 < T_; t0 += 16) {
        float x[16], xc[16], mn[16], dn[16], s[16];
        #pragma unroll
        for (int j = 0; j < 16; ++j) {
            x[j]  = Z[base + (size_t)(t0 + j) * E_];
            mn[j] = stats[(srow + t0 + j) * 2];
            dn[j] = stats[(srow + t0 + j) * 2 + 1];
        }
        #pragma unroll
        for (int j = 0; j < 16; ++j) xc[j] = Xc[base + (size_t)(t0 + j) * E_];
        #pragma unroll
        for (int j = 0; j < 16; ++j) {
            float xn = (x[j] - mn[j]) / dn[j] * gw + bw;
            v = v + (xn - v) * 0.5f;
            s[j] = (v - 1.0f >= 0.0f) ? 1.0f : 0.0f;
            v = v * (1.0f - s[j]);
        }
        #pragma unroll
        for (int j = 0; j < 16; ++j) {
            float nx = xc[j] + s[j];
            Xc[base + (size_t)(t0 + j) * E_] = nx;
            f16 h, hs, lb;
            split3(nx, h, hs, lb);
            At1[base2 + (size_t)(t0 + j) * (2 * E_)]      = *(unsigned short*)&h;
            At1[base2 + (size_t)(t0 + j) * (2 * E_) + E_] = *(unsigned short*)&lb;
        }
        if (lastLayer && t0 + 16 == T_) {
            float nx = Xc[base + (size_t)(T_ - 1) * E_];
            size_t oi = (size_t)(b0 + bb) * E_ + e;
            if (isb) ((bf16*)outp)[oi] = __float2bfloat16(nx);
            else     ((float*)outp)[oi] = nx;
        }
    }
}

// ---------------------------------------------------------------------------
extern "C" void kernel_launch(void* const* d_in, const int* in_sizes, int n_in,
                              void* d_out, int out_size, void* d_ws, size_t ws_size,
                              hipStream_t stream) {
    char* ws = (char*)d_ws;
    int* flag = (int*)ws;
    int* cnts = (int*)(ws + 64);      // 64 ints, header is 512 B total

    const size_t wtCount = 2 * (size_t)E_ * H_;
    const size_t wtBytes = 2 * D_ * wtCount * sizeof(unsigned short); // ~16.8 MB
    unsigned short* Wt1 = (unsigned short*)(ws + 512);
    unsigned short* Wt2 = Wt1 + (size_t)D_ * wtCount;

    size_t used = 512 + wtBytes;
    size_t avail = (ws_size > used) ? ws_size - used : 0;
    // per batch: fp32 bufs + At1 + At2 + stats + LN partials (Pt1 32f, Pt2 16f)
    const size_t perBatch = (size_t)T_ * ((E_ + H_ + E_) * 4 + 2 * E_ * 2 + H_ * 2
                                          + 16 + (32 + 16) * 4);
    int CB = 256;
    while (CB > 1 && (size_t)CB * perBatch > avail) CB >>= 1;
    const int R = CB * T_;

    float* Xc  = (float*)(ws + used);
    float* HBc = Xc + (size_t)R * E_;
    float* Y2c = HBc + (size_t)R * H_;
    unsigned short* At1 = (unsigned short*)(Y2c + (size_t)R * E_);
    unsigned short* At2 = At1 + (size_t)R * 2 * E_;
    float* St1 = (float*)(At2 + (size_t)R * H_);
    float* St2 = St1 + (size_t)R * 2;
    float* Pt1 = St2 + (size_t)R * 2;            // R x 16 slots x 2
    float* Pt2 = Pt1 + (size_t)R * 32;           // R x 8 slots x 2

    sniff_count_kernel<<<64, 256, 0, stream>>>((const unsigned short*)d_in[0], cnts);
    sniff_final_kernel<<<1, 1, 0, stream>>>(cnts, flag);

    for (int d = 0; d < D_; ++d) {
        wsplit_kernel<<<dim3(H_ / 32, E_ / 32), 256, 0, stream>>>(
            d_in[5], (size_t)d * E_ * H_, Wt1 + (size_t)d * wtCount, E_, H_, flag);
        wsplit_kernel<<<dim3(E_ / 32, H_ / 32), 256, 0, stream>>>(
            d_in[9], (size_t)d * H_ * E_, Wt2 + (size_t)d * wtCount, H_, E_, flag);
    }

    for (int b0 = 0; b0 < B_; b0 += CB) {
        proj_kernel<<<R / RB_, 256, 0, stream>>>(d_in[0], d_in[1], d_in[2], d_in[3],
                                                 d_in[4], Xc, At1, (size_t)b0 * T_, flag);
        for (int d = 0; d < D_; ++d) {
            size_t b1o = (size_t)d * H_;
            size_t b2o = (size_t)d * E_;

            gemm_mfma3_kernel<<<(H_ / 128) * (R / 128), 512, 0, stream>>>(
                At1, Wt1 + (size_t)d * wtCount, d_in[6], b1o, HBc, Pt1, H_, E_, flag);
            ln_fin_kernel<<<R / 256, 256, 0, stream>>>(Pt1, 16, St1, H_);
            lif_kernel<<<dim3(H_ / 64, CB), 64, 0, stream>>>(
                HBc, St1, d_in[7], b1o, d_in[8], b1o, At2, H_, flag);

            gemm_mfma2_kernel<<<(E_ / 128) * (R / 128), 256, 0, stream>>>(
                At2, Wt2 + (size_t)d * wtCount, d_in[10], b2o, Y2c, Pt2, E_, H_, flag);
            ln_fin_kernel<<<R / 256, 256, 0, stream>>>(Pt2, 8, St2, E_);
            lif_add_kernel<<<dim3(E_ / 64, CB), 64, 0, stream>>>(
                Y2c, St2, d_in[11], b2o, d_in[12], b2o, Xc, At1,
                d_out, b0, (d == D_ - 1) ? 1 : 0, flag);
        }
    }
}

// Round 21
// 2872.574 us; speedup vs baseline: 1.1963x; 1.0273x over previous
//
#include <hip/hip_runtime.h>
#include <hip/hip_bf16.h>
#include <math.h>

#define B_  256
#define T_  256
#define IN_ 4
#define HP_ 64
#define E_  512
#define H_  1024
#define D_  4

typedef __hip_bfloat16 bf16;
typedef _Float16 f16;
typedef _Float16 f16x8 __attribute__((ext_vector_type(8)));
typedef float f32x4 __attribute__((ext_vector_type(4)));

// ---------------------------------------------------------------------------
// Dual-dtype load helpers: flag!=0 -> input arrays are bf16, else fp32.
// ---------------------------------------------------------------------------
__device__ __forceinline__ float load1(const void* p, size_t idx, bool isb) {
    if (isb) {
        unsigned int u = ((const unsigned short*)p)[idx];
        return __uint_as_float(u << 16);
    }
    return ((const float*)p)[idx];
}

__device__ __forceinline__ float4 load4(const void* p, size_t idx, bool isb) {
    if (isb) {
        ushort4 u = *(const ushort4*)((const unsigned short*)p + idx);
        float4 r;
        r.x = __uint_as_float(((unsigned int)u.x) << 16);
        r.y = __uint_as_float(((unsigned int)u.y) << 16);
        r.z = __uint_as_float(((unsigned int)u.z) << 16);
        r.w = __uint_as_float(((unsigned int)u.w) << 16);
        return r;
    }
    return *((const float4*)p + (idx >> 2));
}

// ---------------------------------------------------------------------------
// Exact 3-plane f16 split:  x ~= h + lb*2^-11  (lb pre-scaled by 2^11).
// x*w = h*wh + (h*2^-11)*(wl*2^11) + (l*2^11)*(wh*2^-11)   [exact terms]
// ---------------------------------------------------------------------------
__device__ __forceinline__ void split3(float x, f16& h, f16& hs, f16& lb) {
    h = (f16)x;
    float hf = (float)h;
    hs = (f16)(hf * 4.8828125e-4f);        // *2^-11 (derived in GEMM)
    lb = (f16)((x - hf) * 2048.0f);        // residual, pre-scaled *2^11
}

// ---------------------------------------------------------------------------
// Dtype sniff, parallelized: 64-block count + 1-thread finalize.
// ---------------------------------------------------------------------------
__global__ void sniff_count_kernel(const unsigned short* __restrict__ p,
                                   int* __restrict__ cnts) {
    __shared__ int cnt;
    if (threadIdx.x == 0) cnt = 0;
    __syncthreads();
    int local = 0;
    #pragma unroll
    for (int k = 0; k < 4; ++k) {
        int i = blockIdx.x * 1024 + k * 256 + threadIdx.x;
        unsigned int bits = ((unsigned int)p[i]) << 16;
        float v = __uint_as_float(bits);
        float a = fabsf(v);
        if (!(a <= 1e4f)) local++;
        else if (v != 0.0f && a < 1e-6f) local++;
    }
    atomicAdd(&cnt, local);
    __syncthreads();
    if (threadIdx.x == 0) cnts[blockIdx.x] = cnt;
}

__global__ void sniff_final_kernel(const int* __restrict__ cnts,
                                   int* __restrict__ flag) {
    int s = 0;
    for (int i = 0; i < 64; ++i) s += cnts[i];
    *flag = (s > 1024) ? 0 : 1;
}

// ---------------------------------------------------------------------------
// Weight transpose+split: W[K][N] -> Wt ushort[N][2K]: [h | lb].
// ---------------------------------------------------------------------------
__global__ __launch_bounds__(256) void wsplit_kernel(
        const void* __restrict__ W, size_t wOff, unsigned short* __restrict__ Wt,
        int K, int N, const int* __restrict__ flag) {
    const bool isb = (*flag != 0);
    __shared__ float tile[32][33];
    const int n0 = blockIdx.x * 32, k0 = blockIdx.y * 32;
    const int t = threadIdx.x;
    {
        int lk = t >> 3, ln0 = (t & 7) << 2;
        float4 v = load4(W, wOff + (size_t)(k0 + lk) * N + n0 + ln0, isb);
        tile[lk][ln0 + 0] = v.x; tile[lk][ln0 + 1] = v.y;
        tile[lk][ln0 + 2] = v.z; tile[lk][ln0 + 3] = v.w;
    }
    __syncthreads();
    int n = t >> 3, kq0 = (t & 7) << 2;
    size_t base = (size_t)(n0 + n) * (2 * (size_t)K) + k0 + kq0;
    #pragma unroll
    for (int j = 0; j < 4; ++j) {
        float x = tile[kq0 + j][n];
        f16 h, hs, lb;
        split3(x, h, hs, lb);
        Wt[base + j]     = *(unsigned short*)&h;
        Wt[base + j + K] = *(unsigned short*)&lb;
    }
}

// ---------------------------------------------------------------------------
// LN partial finalize: per row, sum block partials in FIXED slot order
// (deterministic), mean = S/N, var = S2/N - mean^2 (>=0 guard).
// ---------------------------------------------------------------------------
__global__ __launch_bounds__(256) void ln_fin_kernel(const float* __restrict__ P,
                                                     int ns, float* __restrict__ stats,
                                                     int N) {
    int row = blockIdx.x * 256 + threadIdx.x;
    const float* p = P + (size_t)row * ns * 2;
    float s = 0.f, s2 = 0.f;
    for (int i = 0; i < ns; ++i) {
        s  += p[i * 2];
        s2 += p[i * 2 + 1];
    }
    float mean = s / (float)N;
    float var  = fmaxf(s2 / (float)N - mean * mean, 0.f);
    stats[row * 2]     = mean;
    stats[row * 2 + 1] = sqrtf(var + 1e-5f);
}

// ---------------------------------------------------------------------------
// GEMM1 (3-plane), 512 threads = 8 waves (4x2), wave-tile 32x64, 128x128
// tile, single-buffer 32 KB LDS, 2 barriers/ktile (R18/R20-measured best).
// Epilogue reduces each row's 64-col slice and writes {sum,sumsq} partials
// to Pt[row][bx*2+wn] — feeding ln_fin (replaces the ln_stats re-read).
// ---------------------------------------------------------------------------
__global__ __launch_bounds__(512, 2) void gemm_mfma3_kernel(
        const unsigned short* __restrict__ At, const unsigned short* __restrict__ Wt,
        const void* __restrict__ bias, size_t bOff,
        float* __restrict__ C, float* __restrict__ Pt,
        int N, int K, const int* __restrict__ flag) {
    const bool isb = (*flag != 0);
    __shared__ unsigned short As[128 * 64];      // 16 KB (2 planes)
    __shared__ unsigned short Bs[128 * 64];      // 16 KB (2 planes)

    const int gx = N >> 7;
    const int gy = (int)gridDim.x / gx;
    int bx, by;
    {
        int bid = blockIdx.x;
        if ((gy & 7) == 0) {
            int k = bid & 7, i = bid >> 3;
            bx = i % gx;
            by = (gy >> 3) * k + i / gx;
        } else { bx = bid % gx; by = bid / gx; }
    }
    const int bn = bx * 128;
    const int bm = by * 128;

    const int tid  = threadIdx.x;
    const int lane = tid & 63;
    const int wave = tid >> 6;         // 0..7
    const int wm = wave >> 1;          // 0..3 : 32-row block
    const int wn = wave & 1;           // 0..1 : 64-col block
    const int g  = lane >> 4;          // k-group 0..3
    const int lr = lane & 15;

    const int sar = tid >> 2;          // 0..127 : A/B row
    const int skq = tid & 3;           // k-chunk 0..3 (8 ushorts each)

    const f16 C11 = (f16)4.8828125e-4f;   // 2^-11
    const f16x8 c11v = {C11, C11, C11, C11, C11, C11, C11, C11};

    f32x4 acc[2][4];
    #pragma unroll
    for (int i = 0; i < 2; ++i)
        #pragma unroll
        for (int j = 0; j < 4; ++j) acc[i][j] = (f32x4){0.f, 0.f, 0.f, 0.f};

    const unsigned short* Ap = At + (size_t)(bm + sar) * (2 * (size_t)K) + skq * 8;
    const unsigned short* Wp = Wt + (size_t)(bn + sar) * (2 * (size_t)K) + skq * 8;

    f16x8 av0 = *(const f16x8*)(Ap);
    f16x8 av1 = *(const f16x8*)(Ap + K);
    f16x8 wv0 = *(const f16x8*)(Wp);
    f16x8 wv1 = *(const f16x8*)(Wp + K);

    const int nt = K >> 5;
    for (int t = 0; t < nt; ++t) {
        const int arb = sar * 64, asw = sar & 7;
        *(f16x8*)&As[arb + ((skq ^ asw)) * 8]       = av0;
        *(f16x8*)&As[arb + (((4 | skq) ^ asw)) * 8] = av1;
        *(f16x8*)&Bs[arb + ((skq ^ asw)) * 8]       = wv0;
        *(f16x8*)&Bs[arb + (((4 | skq) ^ asw)) * 8] = wv1;
        __syncthreads();
        if (t + 1 < nt) {
            const int k0 = (t + 1) << 5;
            av0 = *(const f16x8*)(Ap + k0);
            av1 = *(const f16x8*)(Ap + K + k0);
            wv0 = *(const f16x8*)(Wp + k0);
            wv1 = *(const f16x8*)(Wp + K + k0);
        }
        f16x8 a0[2], a2[2], b0[4], b2[4];
        #pragma unroll
        for (int mi = 0; mi < 2; ++mi) {
            const int ar = wm * 32 + mi * 16 + lr;
            a0[mi] = *(const f16x8*)&As[ar * 64 + ((g ^ (ar & 7))) * 8];
            a2[mi] = *(const f16x8*)&As[ar * 64 + (((4 | g) ^ (ar & 7))) * 8];
        }
        #pragma unroll
        for (int ni = 0; ni < 4; ++ni) {
            const int br = wn * 64 + ni * 16 + lr;
            b0[ni] = *(const f16x8*)&Bs[br * 64 + ((g ^ (br & 7))) * 8];
            b2[ni] = *(const f16x8*)&Bs[br * 64 + (((4 | g) ^ (br & 7))) * 8];
        }
        #pragma unroll
        for (int mi = 0; mi < 2; ++mi)
            #pragma unroll
            for (int ni = 0; ni < 4; ++ni)
                acc[mi][ni] = __builtin_amdgcn_mfma_f32_16x16x32_f16(
                    a0[mi], b0[ni], acc[mi][ni], 0, 0, 0);
        {
            f16x8 a1[2];
            #pragma unroll
            for (int mi = 0; mi < 2; ++mi) a1[mi] = a0[mi] * c11v;
            #pragma unroll
            for (int mi = 0; mi < 2; ++mi)
                #pragma unroll
                for (int ni = 0; ni < 4; ++ni)
                    acc[mi][ni] = __builtin_amdgcn_mfma_f32_16x16x32_f16(
                        a1[mi], b2[ni], acc[mi][ni], 0, 0, 0);
        }
        {
            f16x8 b1[4];
            #pragma unroll
            for (int ni = 0; ni < 4; ++ni) b1[ni] = b0[ni] * c11v;
            #pragma unroll
            for (int mi = 0; mi < 2; ++mi)
                #pragma unroll
                for (int ni = 0; ni < 4; ++ni)
                    acc[mi][ni] = __builtin_amdgcn_mfma_f32_16x16x32_f16(
                        a2[mi], b1[ni], acc[mi][ni], 0, 0, 0);
        }
        __syncthreads();
    }
    // ---- epilogue: store C + per-row {sum,sumsq} partials ----
    const int nslot = gx * 2;
    float bvv[4];
    #pragma unroll
    for (int ni = 0; ni < 4; ++ni)
        bvv[ni] = load1(bias, bOff + bn + wn * 64 + ni * 16 + lr, isb);
    #pragma unroll
    for (int mi = 0; mi < 2; ++mi) {
        #pragma unroll
        for (int r = 0; r < 4; ++r) {
            const size_t row = (size_t)(bm + wm * 32 + mi * 16 + g * 4 + r);
            float s = 0.f, s2 = 0.f;
            #pragma unroll
            for (int ni = 0; ni < 4; ++ni) {
                const int col = bn + wn * 64 + ni * 16 + lr;
                float o = acc[mi][ni][r] + bvv[ni];
                C[row * N + col] = o;
                s += o; s2 = fmaf(o, o, s2);
            }
            #pragma unroll
            for (int off = 1; off < 16; off <<= 1) {
                s  += __shfl_xor(s,  off, 64);
                s2 += __shfl_xor(s2, off, 64);
            }
            if (lr == 0) {
                const int slot = bx * 2 + wn;
                Pt[row * (size_t)(2 * nslot) + slot * 2]     = s;
                Pt[row * (size_t)(2 * nslot) + slot * 2 + 1] = s2;
            }
        }
    }
}

// ---------------------------------------------------------------------------
// GEMM2 (2-plane, A = {0,1} spikes): 512 threads = 8 waves (4x2), wave-tile
// 32x64, 128x128 tile, DOUBLE-buffered LDS (one barrier/ktile, R16-proven
// for this grid-limited kernel) — now with the 8-wave residency of R18's
// GEMM1 (16 waves/CU vs 8). Staging/slot/fragment maps lifted verbatim from
// the 8-wave GEMM1 (A: 1 plane, B: 2 planes); per-output MFMA sequence
// unchanged -> bit-identical. Epilogue emits row partials like GEMM1.
// ---------------------------------------------------------------------------
__global__ __launch_bounds__(512, 2) void gemm_mfma2_kernel(
        const unsigned short* __restrict__ At, const unsigned short* __restrict__ Wt,
        const void* __restrict__ bias, size_t bOff,
        float* __restrict__ C, float* __restrict__ Pt,
        int N, int K, const int* __restrict__ flag) {
    const bool isb = (*flag != 0);
    __shared__ unsigned short As[2][128 * 64];   // 32 KB (1 plane used)
    __shared__ unsigned short Bs[2][128 * 64];   // 32 KB (2 planes)

    const int gx = N >> 7;
    const int gy = (int)gridDim.x / gx;
    int bx, by;
    {
        int bid = blockIdx.x;
        if ((gy & 7) == 0) {
            int k = bid & 7, i = bid >> 3;
            bx = i % gx;
            by = (gy >> 3) * k + i / gx;
        } else { bx = bid % gx; by = bid / gx; }
    }
    const int bn = bx * 128;
    const int bm = by * 128;

    const int tid  = threadIdx.x;
    const int lane = tid & 63;
    const int wave = tid >> 6;         // 0..7
    const int wm = wave >> 1;          // 0..3 : 32-row block
    const int wn = wave & 1;           // 0..1 : 64-col block
    const int g  = lane >> 4;
    const int lr = lane & 15;

    const int sar = tid >> 2;          // 0..127 : A/B row
    const int skq = tid & 3;           // k-chunk 0..3

    const f16 C11 = (f16)4.8828125e-4f;
    const f16x8 c11v = {C11, C11, C11, C11, C11, C11, C11, C11};

    f32x4 acc[2][4];
    #pragma unroll
    for (int i = 0; i < 2; ++i)
        #pragma unroll
        for (int j = 0; j < 4; ++j) acc[i][j] = (f32x4){0.f, 0.f, 0.f, 0.f};

    const unsigned short* Ap = At + (size_t)(bm + sar) * (size_t)K + skq * 8;
    const unsigned short* Wp = Wt + (size_t)(bn + sar) * (2 * (size_t)K) + skq * 8;

    f16x8 av0 = *(const f16x8*)(Ap);
    f16x8 wv0 = *(const f16x8*)(Wp);
    f16x8 wv1 = *(const f16x8*)(Wp + K);

    const int nt = K >> 5;
    for (int t = 0; t < nt; ++t) {
        const int cur = t & 1;
        const int arb = sar * 64, asw = sar & 7;
        *(f16x8*)&As[cur][arb + ((skq ^ asw)) * 8]       = av0;
        *(f16x8*)&Bs[cur][arb + ((skq ^ asw)) * 8]       = wv0;
        *(f16x8*)&Bs[cur][arb + (((4 | skq) ^ asw)) * 8] = wv1;
        __syncthreads();
        if (t + 1 < nt) {
            const int k0 = (t + 1) << 5;
            av0 = *(const f16x8*)(Ap + k0);
            wv0 = *(const f16x8*)(Wp + k0);
            wv1 = *(const f16x8*)(Wp + K + k0);
        }
        f16x8 a0[2], b0[4], b2[4];
        #pragma unroll
        for (int mi = 0; mi < 2; ++mi) {
            const int ar = wm * 32 + mi * 16 + lr;
            a0[mi] = *(const f16x8*)&As[cur][ar * 64 + ((g ^ (ar & 7))) * 8];
        }
        #pragma unroll
        for (int ni = 0; ni < 4; ++ni) {
            const int br = wn * 64 + ni * 16 + lr;
            b0[ni] = *(const f16x8*)&Bs[cur][br * 64 + ((g ^ (br & 7))) * 8];
            b2[ni] = *(const f16x8*)&Bs[cur][br * 64 + (((4 | g) ^ (br & 7))) * 8];
        }
        #pragma unroll
        for (int mi = 0; mi < 2; ++mi)
            #pragma unroll
            for (int ni = 0; ni < 4; ++ni)
                acc[mi][ni] = __builtin_amdgcn_mfma_f32_16x16x32_f16(
                    a0[mi], b0[ni], acc[mi][ni], 0, 0, 0);
        {
            f16x8 a1[2];
            #pragma unroll
            for (int mi = 0; mi < 2; ++mi) a1[mi] = a0[mi] * c11v;
            #pragma unroll
            for (int mi = 0; mi < 2; ++mi)
                #pragma unroll
                for (int ni = 0; ni < 4; ++ni)
                    acc[mi][ni] = __builtin_amdgcn_mfma_f32_16x16x32_f16(
                        a1[mi], b2[ni], acc[mi][ni], 0, 0, 0);
        }
        // no trailing barrier: next store goes to the alternate buffer
    }
    // ---- epilogue: store C + per-row {sum,sumsq} partials ----
    const int nslot = gx * 2;
    float bvv[4];
    #pragma unroll
    for (int ni = 0; ni < 4; ++ni)
        bvv[ni] = load1(bias, bOff + bn + wn * 64 + ni * 16 + lr, isb);
    #pragma unroll
    for (int mi = 0; mi < 2; ++mi) {
        #pragma unroll
        for (int r = 0; r < 4; ++r) {
            const size_t row = (size_t)(bm + wm * 32 + mi * 16 + g * 4 + r);
            float s = 0.f, s2 = 0.f;
            #pragma unroll
            for (int ni = 0; ni < 4; ++ni) {
                const int col = bn + wn * 64 + ni * 16 + lr;
                float o = acc[mi][ni][r] + bvv[ni];
                C[row * N + col] = o;
                s += o; s2 = fmaf(o, o, s2);
            }
            #pragma unroll
            for (int off = 1; off < 16; off <<= 1) {
                s  += __shfl_xor(s,  off, 64);
                s2 += __shfl_xor(s2, off, 64);
            }
            if (lr == 0) {
                const int slot = bx * 2 + wn;
                Pt[row * (size_t)(2 * nslot) + slot * 2]     = s;
                Pt[row * (size_t)(2 * nslot) + slot * 2 + 1] = s2;
            }
        }
    }
}

// ---------------------------------------------------------------------------
// Projector: 16 rows/block, loop-swapped phase2; emits Xc fp32 + {h,lb}
// split into At1 (row-major planes at +0 / +E_).
// ---------------------------------------------------------------------------
#define RB_ 16
__global__ __launch_bounds__(256) void proj_kernel(
        const void* __restrict__ hist, const void* __restrict__ pW1,
        const void* __restrict__ pb1,  const void* __restrict__ pW2,
        const void* __restrict__ pb2,  float* __restrict__ Xc,
        unsigned short* __restrict__ At1,
        size_t m0, const int* __restrict__ flag) {
    const bool isb = (*flag != 0);
    __shared__ float h1[RB_][HP_];
    const size_t mb = (size_t)blockIdx.x * RB_;
    const int tid = threadIdx.x;
    const int lane = tid & 63;
    const int grp = tid >> 6;
    #pragma unroll
    for (int rep = 0; rep < 4; ++rep) {
        int idx = tid + rep * 256;
        int r = idx >> 6, c = idx & 63;
        size_t gm = m0 + mb + r;
        float acc = 0.f;
        #pragma unroll
        for (int i = 0; i < IN_; ++i)
            acc = fmaf(load1(hist, gm * IN_ + i, isb),
                       load1(pW1, (size_t)i * HP_ + c, isb), acc);
        acc += load1(pb1, c, isb);
        h1[r][c] = 0.5f * acc * (1.0f + erff(acc * 0.70710678118654752440f));
    }
    __syncthreads();
    const int e0 = lane * 8;
    float acc[4][8];
    #pragma unroll
    for (int r = 0; r < 4; ++r)
        #pragma unroll
        for (int j = 0; j < 8; ++j) acc[r][j] = 0.f;
    for (int i = 0; i < HP_; ++i) {
        float4 wA = load4(pW2, (size_t)i * E_ + e0, isb);
        float4 wB = load4(pW2, (size_t)i * E_ + e0 + 4, isb);
        float w[8] = {wA.x, wA.y, wA.z, wA.w, wB.x, wB.y, wB.z, wB.w};
        #pragma unroll
        for (int r = 0; r < 4; ++r) {
            float h = h1[grp * 4 + r][i];
            #pragma unroll
            for (int j = 0; j < 8; ++j) acc[r][j] = fmaf(h, w[j], acc[r][j]);
        }
    }
    #pragma unroll
    for (int r = 0; r < 4; ++r) {
        size_t row = mb + grp * 4 + r;
        float o[8];
        #pragma unroll
        for (int j = 0; j < 8; ++j)
            o[j] = acc[r][j] + load1(pb2, e0 + j, isb);
        *(float4*)(Xc + row * E_ + e0)     = (float4){o[0], o[1], o[2], o[3]};
        *(float4*)(Xc + row * E_ + e0 + 4) = (float4){o[4], o[5], o[6], o[7]};
        f16x8 hv, lv;
        #pragma unroll
        for (int j = 0; j < 8; ++j) {
            f16 h, hs, lb;
            split3(o[j], h, hs, lb);
            hv[j] = h; lv[j] = lb;
        }
        *(f16x8*)&At1[row * (2 * E_) + e0]      = hv;
        *(f16x8*)&At1[row * (2 * E_) + E_ + e0] = lv;
    }
}

// ---------------------------------------------------------------------------
// LIF scan with fused LN-apply, x16 software pipeline.
// ---------------------------------------------------------------------------
__global__ __launch_bounds__(64) void lif_kernel(const float* __restrict__ Y,
                                                 const float* __restrict__ stats,
                                                 const void* __restrict__ g, size_t gOff,
                                                 const void* __restrict__ b, size_t bOff,
                                                 unsigned short* __restrict__ At2,
                                                 int N, const int* __restrict__ flag) {
    const bool isb = (*flag != 0);
    int f = blockIdx.x * 64 + threadIdx.x;
    int bb = blockIdx.y;
    const float gw = load1(g, gOff + f, isb);
    const float bw = load1(b, bOff + f, isb);
    size_t base = (size_t)bb * T_ * N + f;
    size_t srow = (size_t)bb * T_;
    float v = 0.f;
    for (int t0 = 0; t0 < T_; t0 += 16) {
        float x[16], mn[16], dn[16], s[16];
        #pragma unroll
        for (int j = 0; j < 16; ++j) {
            x[j]  = Y[base + (size_t)(t0 + j) * N];
            mn[j] = stats[(srow + t0 + j) * 2];
            dn[j] = stats[(srow + t0 + j) * 2 + 1];
        }
        #pragma unroll
        for (int j = 0; j < 16; ++j) {
            float xn = (x[j] - mn[j]) / dn[j] * gw + bw;
            v = v + (xn - v) * 0.5f;
            s[j] = (v - 1.0f >= 0.0f) ? 1.0f : 0.0f;
            v = v * (1.0f - s[j]);
        }
        #pragma unroll
        for (int j = 0; j < 16; ++j) {
            f16 h = (f16)s[j];
            At2[base + (size_t)(t0 + j) * N] = *(unsigned short*)&h;
        }
    }
}

// Second LIF: fused LN-apply + residual add into Xc + {h,lb} split to At1.
// When lastLayer!=0 also writes the t=T-1 value to the final output.
__global__ __launch_bounds__(64) void lif_add_kernel(const float* __restrict__ Z,
                                                     const float* __restrict__ stats,
                                                     const void* __restrict__ g, size_t gOff,
                                                     const void* __restrict__ b, size_t bOff,
                                                     float* __restrict__ Xc,
                                                     unsigned short* __restrict__ At1,
                                                     void* __restrict__ outp, int b0,
                                                     int lastLayer,
                                                     const int* __restrict__ flag) {
    const bool isb = (*flag != 0);
    int e = blockIdx.x * 64 + threadIdx.x;
    int bb = blockIdx.y;
    const float gw = load1(g, gOff + e, isb);
    const float bw = load1(b, bOff + e, isb);
    size_t base  = (size_t)bb * T_ * E_ + e;
    size_t base2 = (size_t)bb * T_ * (2 * E_) + e;
    size_t srow  = (size_t)bb * T_;
    float v = 0.f;
    for (int t0 = 0; t0 < T_; t0 += 16) {
        float x[16], xc[16], mn[16], dn[16], s[16];
        #pragma unroll
        for (int j = 0; j < 16; ++j) {
            x[j]  = Z[base + (size_t)(t0 + j) * E_];
            mn[j] = stats[(srow + t0 + j) * 2];
            dn[j] = stats[(srow + t0 + j) * 2 + 1];
        }
        #pragma unroll
        for (int j = 0; j < 16; ++j) xc[j] = Xc[base + (size_t)(t0 + j) * E_];
        #pragma unroll
        for (int j = 0; j < 16; ++j) {
            float xn = (x[j] - mn[j]) / dn[j] * gw + bw;
            v = v + (xn - v) * 0.5f;
            s[j] = (v - 1.0f >= 0.0f) ? 1.0f : 0.0f;
            v = v * (1.0f - s[j]);
        }
        #pragma unroll
        for (int j = 0; j < 16; ++j) {
            float nx = xc[j] + s[j];
            Xc[base + (size_t)(t0 + j) * E_] = nx;
            f16 h, hs, lb;
            split3(nx, h, hs, lb);
            At1[base2 + (size_t)(t0 + j) * (2 * E_)]      = *(unsigned short*)&h;
            At1[base2 + (size_t)(t0 + j) * (2 * E_) + E_] = *(unsigned short*)&lb;
        }
        if (lastLayer && t0 + 16 == T_) {
            float nx = Xc[base + (size_t)(T_ - 1) * E_];
            size_t oi = (size_t)(b0 + bb) * E_ + e;
            if (isb) ((bf16*)outp)[oi] = __float2bfloat16(nx);
            else     ((float*)outp)[oi] = nx;
        }
    }
}

// ---------------------------------------------------------------------------
extern "C" void kernel_launch(void* const* d_in, const int* in_sizes, int n_in,
                              void* d_out, int out_size, void* d_ws, size_t ws_size,
                              hipStream_t stream) {
    char* ws = (char*)d_ws;
    int* flag = (int*)ws;
    int* cnts = (int*)(ws + 64);      // 64 ints, header is 512 B total

    const size_t wtCount = 2 * (size_t)E_ * H_;
    const size_t wtBytes = 2 * D_ * wtCount * sizeof(unsigned short); // ~16.8 MB
    unsigned short* Wt1 = (unsigned short*)(ws + 512);
    unsigned short* Wt2 = Wt1 + (size_t)D_ * wtCount;

    size_t used = 512 + wtBytes;
    size_t avail = (ws_size > used) ? ws_size - used : 0;
    // per batch: fp32 bufs + At1 + At2 + stats + LN partials (Pt1 32f, Pt2 16f)
    const size_t perBatch = (size_t)T_ * ((E_ + H_ + E_) * 4 + 2 * E_ * 2 + H_ * 2
                                          + 16 + (32 + 16) * 4);
    int CB = 256;
    while (CB > 1 && (size_t)CB * perBatch > avail) CB >>= 1;
    const int R = CB * T_;

    float* Xc  = (float*)(ws + used);
    float* HBc = Xc + (size_t)R * E_;
    float* Y2c = HBc + (size_t)R * H_;
    unsigned short* At1 = (unsigned short*)(Y2c + (size_t)R * E_);
    unsigned short* At2 = At1 + (size_t)R * 2 * E_;
    float* St1 = (float*)(At2 + (size_t)R * H_);
    float* St2 = St1 + (size_t)R * 2;
    float* Pt1 = St2 + (size_t)R * 2;            // R x 16 slots x 2
    float* Pt2 = Pt1 + (size_t)R * 32;           // R x 8 slots x 2

    sniff_count_kernel<<<64, 256, 0, stream>>>((const unsigned short*)d_in[0], cnts);
    sniff_final_kernel<<<1, 1, 0, stream>>>(cnts, flag);

    for (int d = 0; d < D_; ++d) {
        wsplit_kernel<<<dim3(H_ / 32, E_ / 32), 256, 0, stream>>>(
            d_in[5], (size_t)d * E_ * H_, Wt1 + (size_t)d * wtCount, E_, H_, flag);
        wsplit_kernel<<<dim3(E_ / 32, H_ / 32), 256, 0, stream>>>(
            d_in[9], (size_t)d * H_ * E_, Wt2 + (size_t)d * wtCount, H_, E_, flag);
    }

    for (int b0 = 0; b0 < B_; b0 += CB) {
        proj_kernel<<<R / RB_, 256, 0, stream>>>(d_in[0], d_in[1], d_in[2], d_in[3],
                                                 d_in[4], Xc, At1, (size_t)b0 * T_, flag);
        for (int d = 0; d < D_; ++d) {
            size_t b1o = (size_t)d * H_;
            size_t b2o = (size_t)d * E_;

            gemm_mfma3_kernel<<<(H_ / 128) * (R / 128), 512, 0, stream>>>(
                At1, Wt1 + (size_t)d * wtCount, d_in[6], b1o, HBc, Pt1, H_, E_, flag);
            ln_fin_kernel<<<R / 256, 256, 0, stream>>>(Pt1, 16, St1, H_);
            lif_kernel<<<dim3(H_ / 64, CB), 64, 0, stream>>>(
                HBc, St1, d_in[7], b1o, d_in[8], b1o, At2, H_, flag);

            gemm_mfma2_kernel<<<(E_ / 128) * (R / 128), 512, 0, stream>>>(
                At2, Wt2 + (size_t)d * wtCount, d_in[10], b2o, Y2c, Pt2, E_, H_, flag);
            ln_fin_kernel<<<R / 256, 256, 0, stream>>>(Pt2, 8, St2, E_);
            lif_add_kernel<<<dim3(E_ / 64, CB), 64, 0, stream>>>(
                Y2c, St2, d_in[11], b2o, d_in[12], b2o, Xc, At1,
                d_out, b0, (d == D_ - 1) ? 1 : 0, flag);
        }
    }
}